// Round 7
// baseline (173.099 us; speedup 1.0000x reference)
//
#include <hip/hip_runtime.h>
#include <hip/hip_cooperative_groups.h>
#include <hip/hip_bf16.h>
#include <math.h>

namespace cg = cooperative_groups;

#define NSENT 256
#define SLEN  512
#define VROWS 50000
#define EDIM  300
#define NROW  12
#define NSTEP 10          // ceil(300/32) K-steps of 16x16x32 MFMA
#define NTILE (VROWS / 16)   // 3125 exact 16-row tiles

typedef __attribute__((ext_vector_type(8))) short bf16x8;
typedef __attribute__((ext_vector_type(4))) float f32x4;

static __device__ __forceinline__ short f2bf(float f) {
    __hip_bfloat16 h = __float2bfloat16(f);
    short s;
    __builtin_memcpy(&s, &h, sizeof(s));
    return s;
}

// ---------------------------------------------------------------------------
// Fused cooperative kernel.
// Phase A: vocab scores s[v][r] = dot(emb[v], k_r) via bf16 MFMA.
//   256 blocks x 16 waves; wave = one 16-row M-tile (3125 tiles, exact).
//   K staged in 2 halves of 5 steps (40 VGPR live, no spills; round-6's
//   20-step batch exceeded the 128-VGPR cap -> scratch traffic).
// grid.sync() (+threadfence) makes the 2.4MB score table visible.
// Phase B: per-sentence gather + windows + tanh + max + fc + log_softmax.
// ---------------------------------------------------------------------------
__global__ __launch_bounds__(1024, 4)
void textcnn_coop(const int*   __restrict__ sent,
                  const float* __restrict__ emb,
                  const float* __restrict__ k3, const float* __restrict__ b3,
                  const float* __restrict__ k4, const float* __restrict__ b4,
                  const float* __restrict__ k5, const float* __restrict__ b5,
                  const float* __restrict__ fcw, const float* __restrict__ fcb,
                  float* __restrict__ out,
                  float* __restrict__ s)
{
    __shared__ float s_lds[NROW * SLEN];
    __shared__ float red[8][3];

    const int tid  = threadIdx.x;
    const int lane = tid & 63;
    const int wave = tid >> 6;      // 0..15
    const int rc   = lane & 15;     // A-row-in-tile / D-col (conv row)
    const int kg   = lane >> 4;     // k-group 0..3

    // ======================= Phase A: vocab scores =========================
    const int vt = blockIdx.x * 16 + wave;    // tile id
    if (vt < NTILE) {
        const int vbase = vt * 16;

        // B fragments: conv-kernel row rc (cols 12..15 zero-padded)
        const float* krow = nullptr;
        if      (rc < 3)  krow = k3 + rc * EDIM;
        else if (rc < 7)  krow = k4 + (rc - 3) * EDIM;
        else if (rc < 12) krow = k5 + (rc - 7) * EDIM;

        bf16x8 bfrag[NSTEP];
        #pragma unroll
        for (int st = 0; st < NSTEP; ++st) {
            const int k0 = st * 32 + kg * 8;
            float4 b0 = make_float4(0.f,0.f,0.f,0.f);
            float4 b1 = make_float4(0.f,0.f,0.f,0.f);
            if (krow) {
                if (k0 + 4 <= EDIM) b0 = *reinterpret_cast<const float4*>(krow + k0);
                if (k0 + 8 <= EDIM) b1 = *reinterpret_cast<const float4*>(krow + k0 + 4);
            }
            bf16x8 f;
            f[0]=f2bf(b0.x); f[1]=f2bf(b0.y); f[2]=f2bf(b0.z); f[3]=f2bf(b0.w);
            f[4]=f2bf(b1.x); f[5]=f2bf(b1.y); f[6]=f2bf(b1.z); f[7]=f2bf(b1.w);
            bfrag[st] = f;
        }

        const float* arow = emb + (size_t)(vbase + rc) * EDIM;
        f32x4 acc = {0.f, 0.f, 0.f, 0.f};

        #pragma unroll
        for (int half = 0; half < 2; ++half) {
            // batch 5 K-steps of A loads (10 float4 = 40 VGPR live)
            float4 a0[5], a1[5];
            #pragma unroll
            for (int i = 0; i < 5; ++i) {
                const int k0 = (half * 5 + i) * 32 + kg * 8;
                a0[i] = (k0 + 4 <= EDIM)
                      ? *reinterpret_cast<const float4*>(arow + k0)
                      : make_float4(0.f,0.f,0.f,0.f);
                a1[i] = (k0 + 8 <= EDIM)
                      ? *reinterpret_cast<const float4*>(arow + k0 + 4)
                      : make_float4(0.f,0.f,0.f,0.f);
            }
            #pragma unroll
            for (int i = 0; i < 5; ++i) {
                bf16x8 af;
                af[0]=f2bf(a0[i].x); af[1]=f2bf(a0[i].y);
                af[2]=f2bf(a0[i].z); af[3]=f2bf(a0[i].w);
                af[4]=f2bf(a1[i].x); af[5]=f2bf(a1[i].y);
                af[6]=f2bf(a1[i].z); af[7]=f2bf(a1[i].w);
                acc = __builtin_amdgcn_mfma_f32_16x16x32_bf16(
                          af, bfrag[half * 5 + i], acc, 0, 0, 0);
            }
        }

        // D: col=lane&15 (conv row), row=kg*4+j (vocab row in tile)
        if (rc < NROW) {
            #pragma unroll
            for (int j = 0; j < 4; ++j)
                s[(size_t)(vbase + kg * 4 + j) * NROW + rc] = acc[j];
        }
    }

    __threadfence();                 // device-scope release of s
    cg::this_grid().sync();          // grid barrier + visibility

    // ======================= Phase B: finish ===============================
    const int b = blockIdx.x;
    const int t = tid;

    auto gather = [&](int token, int j) {
        const int widx = sent[b * SLEN + token];
        const float4 v = reinterpret_cast<const float4*>(s + (size_t)widx * NROW)[j];
        s_lds[(4*j + 0) * SLEN + token] = v.x;
        s_lds[(4*j + 1) * SLEN + token] = v.y;
        s_lds[(4*j + 2) * SLEN + token] = v.z;
        s_lds[(4*j + 3) * SLEN + token] = v.w;
    };

    gather(t & 511, t >> 9);            // j = 0,1 across the 1024 threads
    if (t < SLEN) gather(t, 2);         // j = 2
    __syncthreads();

    if (t < SLEN) {
        const float bb3 = b3[0], bb4 = b4[0], bb5 = b5[0];
        float m3 = -1e30f, m4 = -1e30f, m5 = -1e30f;
        if (t < SLEN - 2)
            m3 = tanhf(s_lds[0*SLEN + t] + s_lds[1*SLEN + t+1] +
                       s_lds[2*SLEN + t+2] + bb3);
        if (t < SLEN - 3)
            m4 = tanhf(s_lds[3*SLEN + t] + s_lds[4*SLEN + t+1] +
                       s_lds[5*SLEN + t+2] + s_lds[6*SLEN + t+3] + bb4);
        if (t < SLEN - 4)
            m5 = tanhf(s_lds[7*SLEN + t] + s_lds[8*SLEN + t+1] +
                       s_lds[9*SLEN + t+2] + s_lds[10*SLEN + t+3] +
                       s_lds[11*SLEN + t+4] + bb5);

        #pragma unroll
        for (int off = 32; off; off >>= 1) {
            m3 = fmaxf(m3, __shfl_xor(m3, off));
            m4 = fmaxf(m4, __shfl_xor(m4, off));
            m5 = fmaxf(m5, __shfl_xor(m5, off));
        }
        if ((t & 63) == 0) {
            const int w = t >> 6;
            red[w][0] = m3; red[w][1] = m4; red[w][2] = m5;
        }
    }
    __syncthreads();

    if (t == 0) {
        float f3 = red[0][0], f4 = red[0][1], f5 = red[0][2];
        #pragma unroll
        for (int w = 1; w < 8; ++w) {
            f3 = fmaxf(f3, red[w][0]);
            f4 = fmaxf(f4, red[w][1]);
            f5 = fmaxf(f5, red[w][2]);
        }
        float lg[10];
        float mx = -1e30f;
        #pragma unroll
        for (int c = 0; c < 10; ++c) {
            lg[c] = fcb[c] + f3 * fcw[c*3+0] + f4 * fcw[c*3+1] + f5 * fcw[c*3+2];
            mx = fmaxf(mx, lg[c]);
        }
        float ssum = 0.f;
        #pragma unroll
        for (int c = 0; c < 10; ++c) ssum += expf(lg[c] - mx);
        const float lse = logf(ssum);
        #pragma unroll
        for (int c = 0; c < 10; ++c) out[b * 10 + c] = lg[c] - mx - lse;
    }
}

extern "C" void kernel_launch(void* const* d_in, const int* in_sizes, int n_in,
                              void* d_out, int out_size, void* d_ws, size_t ws_size,
                              hipStream_t stream) {
    const int*   sent = (const int*)  d_in[0];
    const float* emb  = (const float*)d_in[1];
    const float* k3   = (const float*)d_in[2];
    const float* b3   = (const float*)d_in[3];
    const float* k4   = (const float*)d_in[4];
    const float* b4   = (const float*)d_in[5];
    const float* k5   = (const float*)d_in[6];
    const float* b5   = (const float*)d_in[7];
    const float* fcw  = (const float*)d_in[8];
    const float* fcb  = (const float*)d_in[9];
    float* out = (float*)d_out;
    float* s   = (float*)d_ws;        // VROWS * 12 * 4 B = 2.4 MB

    void* args[] = { (void*)&sent, (void*)&emb,
                     (void*)&k3, (void*)&b3, (void*)&k4, (void*)&b4,
                     (void*)&k5, (void*)&b5, (void*)&fcw, (void*)&fcb,
                     (void*)&out, (void*)&s };
    hipLaunchCooperativeKernel(reinterpret_cast<void*>(textcnn_coop),
                               dim3(NSENT), dim3(1024), args, 0, stream);
}

// Round 8
// 24.572 us; speedup vs baseline: 7.0444x; 7.0444x over previous
//
#include <hip/hip_runtime.h>
#include <hip/hip_bf16.h>
#include <math.h>

#define NSENT 256
#define SLEN  512
#define VROWS 50000
#define EDIM  300
#define NROW  12
#define NSTEP 10          // ceil(300/32) K-steps of 16x16x32 MFMA

typedef __attribute__((ext_vector_type(8))) short bf16x8;
typedef __attribute__((ext_vector_type(4))) float f32x4;

static __device__ __forceinline__ short f2bf(float f) {
    __hip_bfloat16 h = __float2bfloat16(f);   // RNE
    short s;
    __builtin_memcpy(&s, &h, sizeof(s));
    return s;
}

// ---------------------------------------------------------------------------
// Kernel A: vocab scores s[v][r] = dot(emb[v], k_r) via bf16 MFMA.
// Block = 256 thr (4 waves), 64 rows; wave = one 16-row 16x16x32 tile.
// B-fragments live in LDS (10 KB, built once per block) -> frees 40 VGPR;
// A-loads staged in 2 halves of 5 K-steps (40 VGPR live). VGPR ~90 fits the
// launch_bounds(256,4) 128-cap -> 16 waves/CU (round 6 had 8-12 and round 7
// spilled at a 64-VGPR allocation).
// D layout: col=lane&15 (conv row), row=(lane>>4)*4+j (m89-verified).
// ---------------------------------------------------------------------------
__global__ __launch_bounds__(256, 4)
void vocab_scores_mfma(const float* __restrict__ emb,
                       const float* __restrict__ k3,
                       const float* __restrict__ k4,
                       const float* __restrict__ k5,
                       float* __restrict__ s)
{
    __shared__ bf16x8 bfrag_lds[NSTEP * 64];   // 10 KB

    const int tid  = threadIdx.x;
    const int lane = tid & 63;
    const int wave = tid >> 6;      // 0..3
    const int rc   = lane & 15;     // A-row-in-tile / D-col (conv row)
    const int kg   = lane >> 4;     // k-group 0..3

    // ---- build B fragments cooperatively (weights ~14KB, L1/L2-hot) ------
    for (int e = tid; e < NSTEP * 64; e += 256) {
        const int st  = e >> 6;
        const int le  = e & 63;
        const int rce = le & 15;
        const int kge = le >> 4;
        const float* krow = nullptr;
        if      (rce < 3)  krow = k3 + rce * EDIM;
        else if (rce < 7)  krow = k4 + (rce - 3) * EDIM;
        else if (rce < 12) krow = k5 + (rce - 7) * EDIM;
        const int k0 = st * 32 + kge * 8;
        float4 b0 = make_float4(0.f,0.f,0.f,0.f);
        float4 b1 = make_float4(0.f,0.f,0.f,0.f);
        if (krow) {
            if (k0 + 4 <= EDIM) b0 = *reinterpret_cast<const float4*>(krow + k0);
            if (k0 + 8 <= EDIM) b1 = *reinterpret_cast<const float4*>(krow + k0 + 4);
        }
        bf16x8 f;
        f[0]=f2bf(b0.x); f[1]=f2bf(b0.y); f[2]=f2bf(b0.z); f[3]=f2bf(b0.w);
        f[4]=f2bf(b1.x); f[5]=f2bf(b1.y); f[6]=f2bf(b1.z); f[7]=f2bf(b1.w);
        bfrag_lds[e] = f;
    }
    __syncthreads();

    const int vbase = blockIdx.x * 64 + wave * 16;
    const int vrow  = min(vbase + rc, VROWS - 1);    // clamp tail; stores guarded
    const float* arow = emb + (size_t)vrow * EDIM;

    f32x4 acc = {0.f, 0.f, 0.f, 0.f};

    #pragma unroll
    for (int half = 0; half < 2; ++half) {
        // batch 5 K-steps of A loads (10 float4 = 40 VGPR live)
        float4 a0[5], a1[5];
        #pragma unroll
        for (int i = 0; i < 5; ++i) {
            const int k0 = (half * 5 + i) * 32 + kg * 8;
            a0[i] = (k0 + 4 <= EDIM)
                  ? *reinterpret_cast<const float4*>(arow + k0)
                  : make_float4(0.f,0.f,0.f,0.f);
            a1[i] = (k0 + 8 <= EDIM)
                  ? *reinterpret_cast<const float4*>(arow + k0 + 4)
                  : make_float4(0.f,0.f,0.f,0.f);
        }
        #pragma unroll
        for (int i = 0; i < 5; ++i) {
            const int st = half * 5 + i;
            const bf16x8 bf = bfrag_lds[st * 64 + lane];   // ds_read_b128
            bf16x8 af;
            af[0]=f2bf(a0[i].x); af[1]=f2bf(a0[i].y);
            af[2]=f2bf(a0[i].z); af[3]=f2bf(a0[i].w);
            af[4]=f2bf(a1[i].x); af[5]=f2bf(a1[i].y);
            af[6]=f2bf(a1[i].z); af[7]=f2bf(a1[i].w);
            acc = __builtin_amdgcn_mfma_f32_16x16x32_bf16(af, bf, acc, 0, 0, 0);
        }
    }

    // store D: 4 vocab rows per lane-group
    if (rc < NROW) {
        #pragma unroll
        for (int j = 0; j < 4; ++j) {
            const int v = vbase + kg * 4 + j;
            if (v < VROWS) s[(size_t)v * NROW + rc] = acc[j];
        }
    }
}

// ---------------------------------------------------------------------------
// Kernel B: gather 48B/token from L2/L3-resident score table, then
// windows + tanh + max + fc + log_softmax. One block (1024 thr) per sentence.
// ---------------------------------------------------------------------------
__global__ __launch_bounds__(1024, 1)
void textcnn_finish(const int*   __restrict__ sent,
                    const float* __restrict__ s,
                    const float* __restrict__ b3,
                    const float* __restrict__ b4,
                    const float* __restrict__ b5,
                    const float* __restrict__ fcw,
                    const float* __restrict__ fcb,
                    float* __restrict__ out)
{
    __shared__ float s_lds[NROW * SLEN];
    __shared__ float red[8][3];

    const int b = blockIdx.x;
    const int t = threadIdx.x;

    auto gather = [&](int token, int j) {
        const int widx = sent[b * SLEN + token];
        const float4 v = reinterpret_cast<const float4*>(s + (size_t)widx * NROW)[j];
        s_lds[(4*j + 0) * SLEN + token] = v.x;
        s_lds[(4*j + 1) * SLEN + token] = v.y;
        s_lds[(4*j + 2) * SLEN + token] = v.z;
        s_lds[(4*j + 3) * SLEN + token] = v.w;
    };

    gather(t & 511, t >> 9);            // j = 0,1 across the 1024 threads
    if (t < SLEN) gather(t, 2);         // j = 2
    __syncthreads();

    if (t < SLEN) {
        const float bb3 = b3[0], bb4 = b4[0], bb5 = b5[0];
        float m3 = -1e30f, m4 = -1e30f, m5 = -1e30f;
        if (t < SLEN - 2)
            m3 = tanhf(s_lds[0*SLEN + t] + s_lds[1*SLEN + t+1] +
                       s_lds[2*SLEN + t+2] + bb3);
        if (t < SLEN - 3)
            m4 = tanhf(s_lds[3*SLEN + t] + s_lds[4*SLEN + t+1] +
                       s_lds[5*SLEN + t+2] + s_lds[6*SLEN + t+3] + bb4);
        if (t < SLEN - 4)
            m5 = tanhf(s_lds[7*SLEN + t] + s_lds[8*SLEN + t+1] +
                       s_lds[9*SLEN + t+2] + s_lds[10*SLEN + t+3] +
                       s_lds[11*SLEN + t+4] + bb5);

        #pragma unroll
        for (int off = 32; off; off >>= 1) {
            m3 = fmaxf(m3, __shfl_xor(m3, off));
            m4 = fmaxf(m4, __shfl_xor(m4, off));
            m5 = fmaxf(m5, __shfl_xor(m5, off));
        }
        if ((t & 63) == 0) {
            const int w = t >> 6;
            red[w][0] = m3; red[w][1] = m4; red[w][2] = m5;
        }
    }
    __syncthreads();

    if (t == 0) {
        float f3 = red[0][0], f4 = red[0][1], f5 = red[0][2];
        #pragma unroll
        for (int w = 1; w < 8; ++w) {
            f3 = fmaxf(f3, red[w][0]);
            f4 = fmaxf(f4, red[w][1]);
            f5 = fmaxf(f5, red[w][2]);
        }
        float lg[10];
        float mx = -1e30f;
        #pragma unroll
        for (int c = 0; c < 10; ++c) {
            lg[c] = fcb[c] + f3 * fcw[c*3+0] + f4 * fcw[c*3+1] + f5 * fcw[c*3+2];
            mx = fmaxf(mx, lg[c]);
        }
        float ssum = 0.f;
        #pragma unroll
        for (int c = 0; c < 10; ++c) ssum += expf(lg[c] - mx);
        const float lse = logf(ssum);
        #pragma unroll
        for (int c = 0; c < 10; ++c) out[b * 10 + c] = lg[c] - mx - lse;
    }
}

extern "C" void kernel_launch(void* const* d_in, const int* in_sizes, int n_in,
                              void* d_out, int out_size, void* d_ws, size_t ws_size,
                              hipStream_t stream) {
    const int*   sent = (const int*)  d_in[0];
    const float* emb  = (const float*)d_in[1];
    const float* k3   = (const float*)d_in[2];
    const float* b3   = (const float*)d_in[3];
    const float* k4   = (const float*)d_in[4];
    const float* b4   = (const float*)d_in[5];
    const float* k5   = (const float*)d_in[6];
    const float* b5   = (const float*)d_in[7];
    const float* fcw  = (const float*)d_in[8];
    const float* fcb  = (const float*)d_in[9];
    float* out = (float*)d_out;
    float* s   = (float*)d_ws;        // VROWS * 12 * 4 B = 2.4 MB

    const int nblk = (VROWS + 63) / 64;   // 782 blocks, 64 rows each
    vocab_scores_mfma<<<nblk, 256, 0, stream>>>(emb, k3, k4, k5, s);
    textcnn_finish<<<NSENT, 1024, 0, stream>>>(sent, s, b3, b4, b5, fcw, fcb, out);
}